// Round 8
// baseline (102.801 us; speedup 1.0000x reference)
//
#include <hip/hip_runtime.h>

// Problem constants (from reference)
#define BATCH 16
#define HH 1024
#define WW 2048
#define HWPIX (HH * WW)            // 2,097,152 pixels per batch
#define NID 255                    // ids 101..355 -> index 0..254

#define THREADS 1024
#define SLICES 32                  // blocks per batch; 16*32 = 512 blocks
#define PIX_PER_BLOCK (HWPIX / SLICES)        // 65536 (32 rows of 2048)
#define ROWS_PER_BLOCK 32
#define ITERS (PIX_PER_BLOCK / (THREADS * 4)) // 16
#define NCOL 32                    // u64 columns per id (lane-pair private)
#define NBLK (BATCH * SLICES)      // 512
#define PSTR 13                    // flush-part stride (bank-friendly)

typedef unsigned long long u64;
typedef unsigned u32;

#define AGENT __HIP_MEMORY_SCOPE_AGENT
#define LDA(p)    __hip_atomic_load((p),  __ATOMIC_RELAXED, AGENT)
#define STA(p, v) __hip_atomic_store((p), (v), __ATOMIC_RELAXED, AGENT)

// Cell u64 per (id, lane-pair): exposure <= 2 lanes * 64 px = 128 px.
//   [0,24)  sum_x      (max 128*2047 = 262,016 < 2^24)
//   [24,40) sum_y_rel  (max 128*31   = 3,968   < 2^16)
//   [40,..) count      (max 128)
// Overflow-free for ANY data; same-address only when paired lanes share an id.
//
// Cross-block handoff: all partials are AGENT-scope atomic stores/loads
// (coherent across XCDs, bypass stale L1 across graph replays); per-batch
// done-counter elects the 32nd block as batch-combiner; 16th combiner does
// the final reduce. No spin-waits -> deadlock-free by construction.

__global__ __launch_bounds__(THREADS) void accum_kernel(
    const float* __restrict__ logits, const int* __restrict__ label,
    u32* __restrict__ g_cnt, u32* __restrict__ g_sx, u32* __restrict__ g_sy,
    double* __restrict__ g_bexp_part, double* __restrict__ g_bexp,
    float* __restrict__ g_binst, u32* __restrict__ g_done,  // [BATCH] batch ctrs + [1] final ctr
    float* __restrict__ out)
{
    __shared__ u64 table[NID * NCOL];      // 65,280 B
    __shared__ u32 part[NID * PSTR];       // 13,260 B
    __shared__ double exp_lds[16];
    __shared__ float red[256];
    __shared__ int flag;

    const int tid  = threadIdx.x;
    const int lane = tid & 63;
    const int col  = lane >> 1;            // lane-pair column
    const int blk   = blockIdx.x;
    const int batch = blk >> 5;
    const int slice = blk & 31;

    for (int i = tid; i < NID * NCOL; i += THREADS) table[i] = 0ull;
    __syncthreads();

    const float4* lg4 = (const float4*)logits + (size_t)batch * (HWPIX / 4) + slice * (PIX_PER_BLOCK / 4);
    const int4*   lb4 = (const int4*)label   + (size_t)batch * (HWPIX / 4) + slice * (PIX_PER_BLOCK / 4);

    float es = 0.f;
#pragma unroll 4
    for (int i = 0; i < ITERS; ++i) {
        const int g = i * THREADS + tid;          // float4-group within slice
        const float4 f  = lg4[g];
        const int4   lb = lb4[g];
        es += __expf(f.x) + __expf(f.y) + __expf(f.z) + __expf(f.w);
        const int p0 = g << 2;                    // pixel index within slice
        const int yr = p0 >> 11;                  // local row (0..31)
        const int x0 = p0 & 2047;
        const u64 base = ((u64)1 << 40) | ((u64)yr << 24);
        if (lb.x > 100) atomicAdd(&table[(lb.x - 101) * NCOL + col], base | (u64)(x0 + 0));
        if (lb.y > 100) atomicAdd(&table[(lb.y - 101) * NCOL + col], base | (u64)(x0 + 1));
        if (lb.z > 100) atomicAdd(&table[(lb.z - 101) * NCOL + col], base | (u64)(x0 + 2));
        if (lb.w > 100) atomicAdd(&table[(lb.w - 101) * NCOL + col], base | (u64)(x0 + 3));
    }

    // exp partial: wave shuffle reduce -> LDS
    for (int off = 32; off > 0; off >>= 1) es += __shfl_down(es, off, 64);
    if (lane == 0) exp_lds[tid >> 6] = (double)es;
    __syncthreads();

    // flush stage A: 4 threads per id, 8 u64 cells each -> LDS partials
    {
        const int fid  = tid >> 2;
        const int fsub = tid & 3;
        if (fid < NID) {
            u32 cnt_a = 0, sx_a = 0, syr_a = 0;
            const u64* cp = &table[fid * NCOL + fsub * 8];
#pragma unroll
            for (int j = 0; j < 8; ++j) {
                const u64 v = cp[j];
                cnt_a += (u32)(v >> 40);
                syr_a += (u32)((v >> 24) & 0xFFFFu);
                sx_a  += (u32)(v & 0xFFFFFFu);
            }
            part[fid * PSTR + fsub * 3 + 0] = cnt_a;
            part[fid * PSTR + fsub * 3 + 1] = sx_a;
            part[fid * PSTR + fsub * 3 + 2] = syr_a;
        }
    }
    __syncthreads();

    // exp: block partial (coherent store — read later by combiner block)
    if (tid == 0) {
        double t = 0.0;
        for (int w = 0; w < 16; ++w) t += exp_lds[w];
        STA(&g_bexp_part[blk], t);
    }

    // flush stage B: one thread per id, coherent stores (ALL ids incl. zero)
    if (tid < NID) {
        u32 cnt_t = 0, sx_t = 0, syr_t = 0;
        for (int q = 0; q < 4; ++q) {
            cnt_t += part[tid * PSTR + q * 3 + 0];
            sx_t  += part[tid * PSTR + q * 3 + 1];
            syr_t += part[tid * PSTR + q * 3 + 2];
        }
        const size_t o = (size_t)blk * NID + tid;
        STA(&g_cnt[o], cnt_t);
        STA(&g_sx [o], sx_t);
        STA(&g_sy [o], syr_t + (u32)(slice * ROWS_PER_BLOCK) * cnt_t);
    }
    __syncthreads();   // compiler drains vmcnt before barrier -> stores issued

    // elect batch-combiner: last of the batch's 32 blocks
    if (tid == 0) {
        __threadfence();
        const u32 prev = __hip_atomic_fetch_add(&g_done[batch], 1u, __ATOMIC_ACQ_REL, AGENT);
        flag = (prev == SLICES - 1);
    }
    __syncthreads();
    if (!flag) return;
    __threadfence();

    // ===== per-batch combine (one block per batch reaches here) =====
    double e_b = 0.0;                      // batch exp total (ends in tid 0)
    if (tid < 64) {
        if (tid < SLICES) e_b = LDA(&g_bexp_part[batch * SLICES + tid]);
        for (int off = 32; off > 0; off >>= 1) e_b += __shfl_down(e_b, off, 64);
    }
    {
        const int id = tid >> 2;
        const int q  = tid & 3;            // 8 slices per quarter
        if (id < NID) {
            u32 c = 0, x = 0, y = 0;
            for (int s = 0; s < 8; ++s) {
                const size_t o = ((size_t)batch * SLICES + q * 8 + s) * NID + id;
                c += LDA(&g_cnt[o]);
                x += LDA(&g_sx [o]);
                y += LDA(&g_sy [o]);
            }
            part[id * PSTR + q * 3 + 0] = c;
            part[id * PSTR + q * 3 + 1] = x;
            part[id * PSTR + q * 3 + 2] = y;
        }
    }
    __syncthreads();

    float s = 0.f;
    if (tid < NID) {                       // id = 101 + tid
        u32 c = 0, x = 0, y = 0;
        for (int q = 0; q < 4; ++q) {
            c += part[tid * PSTR + q * 3 + 0];
            x += part[tid * PSTR + q * 3 + 1];
            y += part[tid * PSTR + q * 3 + 2];
        }
        if (c) {
            const float fc = (float)c;
            // identical f32 divide + truncation as the reference
            const int cx = (int)((float)x / fc);
            const int cy = (int)((float)y / fc);
            s = logits[(size_t)batch * HWPIX + (size_t)cy * WW + cx];
        }
    }
    if (tid < 256) red[tid] = (tid < NID) ? s : 0.f;
    __syncthreads();
    for (int off = 128; off > 0; off >>= 1) {
        if (tid < off) red[tid] += red[tid + off];
        __syncthreads();
    }

    if (tid == 0) {
        STA(&g_binst[batch], red[0]);
        STA(&g_bexp [batch], e_b);
        __threadfence();
        const u32 prev = __hip_atomic_fetch_add(&g_done[BATCH], 1u, __ATOMIC_ACQ_REL, AGENT);
        flag = (prev == BATCH - 1);
    }
    __syncthreads();
    if (!flag) return;
    __threadfence();

    // ===== final (one block device-wide reaches here) =====
    if (tid < 64) {
        double e = 0.0, inst = 0.0;
        if (tid < BATCH) {
            e    = LDA(&g_bexp [tid]);
            inst = (double)LDA(&g_binst[tid]);
        }
        for (int off = 32; off > 0; off >>= 1) {
            e    += __shfl_down(e,    off, 64);
            inst += __shfl_down(inst, off, 64);
        }
        if (tid == 0) {
            const double int_loss = e / (double)((double)BATCH * (double)HWPIX);
            out[0] = (float)(int_loss - inst / (double)BATCH);
        }
    }
}

extern "C" void kernel_launch(void* const* d_in, const int* in_sizes, int n_in,
                              void* d_out, int out_size, void* d_ws, size_t ws_size,
                              hipStream_t stream) {
    const float* logits = (const float*)d_in[0];
    const int*   label  = (const int*)d_in[1];
    float* out = (float*)d_out;

    // workspace layout (partials fully rewritten every call -> no memset;
    // only the 68-byte counter region needs zeroing each call)
    u32*    g_cnt       = (u32*)d_ws;                             // 512*255 u32
    u32*    g_sx        = g_cnt + (size_t)NBLK * NID;
    u32*    g_sy        = g_sx  + (size_t)NBLK * NID;
    double* g_bexp_part = (double*)(g_sy + (size_t)NBLK * NID);   // 512 f64 (offset 1,566,720 — 8-aligned)
    double* g_bexp      = g_bexp_part + NBLK;                     // 16 f64
    float*  g_binst     = (float*)(g_bexp + BATCH);               // 16 f32
    u32*    g_done      = (u32*)(g_binst + BATCH);                // 16+1 u32 counters

    hipMemsetAsync(g_done, 0, (BATCH + 1) * sizeof(u32), stream);
    accum_kernel<<<NBLK, THREADS, 0, stream>>>(logits, label, g_cnt, g_sx, g_sy,
                                               g_bexp_part, g_bexp, g_binst, g_done, out);
}

// Round 9
// 60.151 us; speedup vs baseline: 1.7090x; 1.7090x over previous
//
#include <hip/hip_runtime.h>

// Problem constants (from reference)
#define BATCH 16
#define HH 1024
#define WW 2048
#define HWPIX (HH * WW)            // 2,097,152 pixels per batch
#define NID 255                    // ids 101..355 -> index 0..254

#define THREADS 1024
#define SLICES 32                  // blocks per batch; 16*32 = 512 blocks = 2/CU
#define PIX_PER_BLOCK (HWPIX / SLICES)        // 65536 (32 rows of 2048)
#define ROWS_PER_BLOCK 32
#define ITERS (PIX_PER_BLOCK / (THREADS * 4)) // 16
#define NCOL 32                    // u64 columns per id (lane-pair private)
#define NBLK (BATCH * SLICES)      // 512
#define PSTR 13                    // flush-part stride (bank-friendly)

typedef unsigned long long u64;
typedef unsigned u32;

// Cell u64 per (id, lane-pair): exposure <= 2 lanes * 64 px = 128 px.
//   [0,24)  sum_x      (max 128*2047 = 262,016 < 2^24)
//   [24,40) sum_y_rel  (max 128*31   = 3,968   < 2^16)
//   [40,..) count      (max 128)
// Overflow-free for ANY data; same-address only when paired lanes share an id.
// Measured wall (R2/R3/R5/R6/R7): ~51 cyc per DS-atomic wave-instr -> accum
// is at its structural floor; everything else is tail overhead.

__global__ __launch_bounds__(THREADS) void accum_kernel(
    const float* __restrict__ logits, const int* __restrict__ label,
    u32* __restrict__ g_cnt, u32* __restrict__ g_sx, u32* __restrict__ g_sy,
    double* __restrict__ g_bexp_part)
{
    __shared__ u64 table[NID * NCOL];      // 65,280 B
    __shared__ u32 part[NID * PSTR];       // 13,260 B
    __shared__ double exp_lds[16];

    const int tid  = threadIdx.x;
    const int lane = tid & 63;
    const int col  = lane >> 1;            // lane-pair column
    const int blk   = blockIdx.x;
    const int batch = blk >> 5;
    const int slice = blk & 31;

    for (int i = tid; i < NID * NCOL; i += THREADS) table[i] = 0ull;
    __syncthreads();

    const float4* lg4 = (const float4*)logits + (size_t)batch * (HWPIX / 4) + slice * (PIX_PER_BLOCK / 4);
    const int4*   lb4 = (const int4*)label   + (size_t)batch * (HWPIX / 4) + slice * (PIX_PER_BLOCK / 4);

    float es = 0.f;
#pragma unroll 4
    for (int i = 0; i < ITERS; ++i) {
        const int g = i * THREADS + tid;          // float4-group within slice
        const float4 f  = lg4[g];
        const int4   lb = lb4[g];
        es += __expf(f.x) + __expf(f.y) + __expf(f.z) + __expf(f.w);
        const int p0 = g << 2;                    // pixel index within slice
        const int yr = p0 >> 11;                  // local row (0..31)
        const int x0 = p0 & 2047;
        const u64 base = ((u64)1 << 40) | ((u64)yr << 24);
        if (lb.x > 100) atomicAdd(&table[(lb.x - 101) * NCOL + col], base | (u64)(x0 + 0));
        if (lb.y > 100) atomicAdd(&table[(lb.y - 101) * NCOL + col], base | (u64)(x0 + 1));
        if (lb.z > 100) atomicAdd(&table[(lb.z - 101) * NCOL + col], base | (u64)(x0 + 2));
        if (lb.w > 100) atomicAdd(&table[(lb.w - 101) * NCOL + col], base | (u64)(x0 + 3));
    }

    // exp partial: wave shuffle reduce -> LDS
    for (int off = 32; off > 0; off >>= 1) es += __shfl_down(es, off, 64);
    if (lane == 0) exp_lds[tid >> 6] = (double)es;
    __syncthreads();

    // flush stage A: 4 threads per id, 8 u64 cells each -> LDS partials
    {
        const int fid  = tid >> 2;
        const int fsub = tid & 3;
        if (fid < NID) {
            u32 cnt_a = 0, sx_a = 0, syr_a = 0;
            const u64* cp = &table[fid * NCOL + fsub * 8];
#pragma unroll
            for (int j = 0; j < 8; ++j) {
                const u64 v = cp[j];
                cnt_a += (u32)(v >> 40);
                syr_a += (u32)((v >> 24) & 0xFFFFu);
                sx_a  += (u32)(v & 0xFFFFFFu);
            }
            part[fid * PSTR + fsub * 3 + 0] = cnt_a;
            part[fid * PSTR + fsub * 3 + 1] = sx_a;
            part[fid * PSTR + fsub * 3 + 2] = syr_a;
        }
    }
    __syncthreads();

    // exp: block partial -> ONE plain f64 store (block-private, no memset)
    if (tid == 0) {
        double t = 0.0;
        for (int w = 0; w < 16; ++w) t += exp_lds[w];
        g_bexp_part[blk] = t;
    }

    // flush stage B: one thread per id, plain stores (write ALL ids incl. zero)
    if (tid < NID) {
        u32 cnt_t = 0, sx_t = 0, syr_t = 0;
        for (int q = 0; q < 4; ++q) {
            cnt_t += part[tid * PSTR + q * 3 + 0];
            sx_t  += part[tid * PSTR + q * 3 + 1];
            syr_t += part[tid * PSTR + q * 3 + 2];
        }
        const size_t o = (size_t)blk * NID + tid;
        g_cnt[o] = cnt_t;
        g_sx [o] = sx_t;
        g_sy [o] = syr_t + (u32)(slice * ROWS_PER_BLOCK) * cnt_t;
    }
}

// One block per batch: combine 32 slice-partials, gather centroids, and
// atomicAdd this batch's closed-form loss term directly into out[0]
// (out zeroed by a 4-byte memset each call -> deterministic per replay).
__global__ __launch_bounds__(256) void batch_kernel(
    const float* __restrict__ logits, const u32* __restrict__ g_cnt,
    const u32* __restrict__ g_sx, const u32* __restrict__ g_sy,
    const double* __restrict__ g_bexp_part, float* __restrict__ out)
{
    const int b   = blockIdx.x;
    const int tid = threadIdx.x;

    __shared__ double e_sh;
    if (tid < 64) {
        double e = (tid < SLICES) ? g_bexp_part[b * SLICES + tid] : 0.0;
        for (int off = 32; off > 0; off >>= 1) e += __shfl_down(e, off, 64);
        if (tid == 0) e_sh = e;
    }

    float s = 0.f;
    if (tid < NID) {                   // id = 101 + tid
        u32 cnt = 0, sx = 0, sy = 0;
        for (int sl = 0; sl < SLICES; ++sl) {
            const size_t o = ((size_t)b * SLICES + sl) * NID + tid;  // coalesced over tid
            cnt += g_cnt[o];
            sx  += g_sx [o];
            sy  += g_sy [o];
        }
        if (cnt) {
            const float fc = (float)cnt;
            // identical f32 divide + truncation as the reference
            const int cx = (int)((float)sx / fc);
            const int cy = (int)((float)sy / fc);
            s = logits[(size_t)b * HWPIX + (size_t)cy * WW + cx];
        }
    }
    __shared__ float red[256];
    red[tid] = s;
    __syncthreads();
    for (int off = 128; off > 0; off >>= 1) {
        if (tid < off) red[tid] += red[tid + off];
        __syncthreads();
    }
    if (tid == 0) {
        const double term = e_sh / (double)((double)BATCH * (double)HWPIX)
                          - (double)red[0] / (double)BATCH;
        atomicAdd(out, (float)term);
    }
}

extern "C" void kernel_launch(void* const* d_in, const int* in_sizes, int n_in,
                              void* d_out, int out_size, void* d_ws, size_t ws_size,
                              hipStream_t stream) {
    const float* logits = (const float*)d_in[0];
    const int*   label  = (const int*)d_in[1];
    float* out = (float*)d_out;

    // workspace layout (all regions fully rewritten every call -> no ws memset)
    u32*    g_cnt       = (u32*)d_ws;                             // 512*255 u32
    u32*    g_sx        = g_cnt + (size_t)NBLK * NID;
    u32*    g_sy        = g_sx  + (size_t)NBLK * NID;
    double* g_bexp_part = (double*)(g_sy + (size_t)NBLK * NID);   // 512 f64 (8-aligned)

    hipMemsetAsync(out, 0, sizeof(float), stream);                // out accumulated via atomicAdd
    accum_kernel<<<NBLK, THREADS, 0, stream>>>(logits, label, g_cnt, g_sx, g_sy, g_bexp_part);
    batch_kernel<<<BATCH, 256, 0, stream>>>(logits, g_cnt, g_sx, g_sy, g_bexp_part, out);
}

// Round 10
// 54.228 us; speedup vs baseline: 1.8957x; 1.1092x over previous
//
#include <hip/hip_runtime.h>

// Problem constants (from reference)
#define BATCH 16
#define HH 1024
#define WW 2048
#define HWPIX (HH * WW)            // 2,097,152 pixels per batch
#define NID 255                    // ids 101..355 -> index 0..254

#define THREADS 1024
#define SLICES 32                  // blocks per batch; 16*32 = 512 blocks = 2/CU
#define PIX_PER_BLOCK (HWPIX / SLICES)        // 65536 (32 rows of 2048)
#define ROWS_PER_BLOCK 32
#define ITERS (PIX_PER_BLOCK / (THREADS * 4)) // 16
#define NCOL 32                    // u64 columns per id (lane-pair private)
#define NBLK (BATCH * SLICES)      // 512
#define PSTR 13                    // flush-part stride (bank-friendly)

typedef unsigned long long u64;
typedef unsigned u32;

// Cell u64 per (id, lane-pair): exposure <= 2 lanes * 64 px = 128 px.
//   [0,24)  sum_x      (max 128*2047 = 262,016 < 2^24)
//   [24,40) sum_y_rel  (max 128*31   = 3,968   < 2^16)
//   [40,..) count      (max 128)
// Overflow-free for ANY data; same-address only when paired lanes share an id.
// Measured wall (R2..R9): ~51 cyc per DS-atomic wave-instr -> accum is at its
// structural floor; R7's plain-store tail is the cheapest handoff measured.

__global__ __launch_bounds__(THREADS) void accum_kernel(
    const float* __restrict__ logits, const int* __restrict__ label,
    u32* __restrict__ g_cnt, u32* __restrict__ g_sx, u32* __restrict__ g_sy,
    double* __restrict__ g_bexp_part)
{
    __shared__ u64 table[NID * NCOL];      // 65,280 B
    __shared__ u32 part[NID * PSTR];       // 13,260 B
    __shared__ double exp_lds[16];

    const int tid  = threadIdx.x;
    const int lane = tid & 63;
    const int col  = lane >> 1;            // lane-pair column
    const int blk   = blockIdx.x;
    const int batch = blk >> 5;
    const int slice = blk & 31;

    for (int i = tid; i < NID * NCOL; i += THREADS) table[i] = 0ull;
    __syncthreads();

    const float4* lg4 = (const float4*)logits + (size_t)batch * (HWPIX / 4) + slice * (PIX_PER_BLOCK / 4);
    const int4*   lb4 = (const int4*)label   + (size_t)batch * (HWPIX / 4) + slice * (PIX_PER_BLOCK / 4);

    float es = 0.f;
#pragma unroll 4
    for (int i = 0; i < ITERS; ++i) {
        const int g = i * THREADS + tid;          // float4-group within slice
        const float4 f  = lg4[g];
        const int4   lb = lb4[g];
        es += __expf(f.x) + __expf(f.y) + __expf(f.z) + __expf(f.w);
        const int p0 = g << 2;                    // pixel index within slice
        const int yr = p0 >> 11;                  // local row (0..31)
        const int x0 = p0 & 2047;
        const u64 base = ((u64)1 << 40) | ((u64)yr << 24);
        if (lb.x > 100) atomicAdd(&table[(lb.x - 101) * NCOL + col], base | (u64)(x0 + 0));
        if (lb.y > 100) atomicAdd(&table[(lb.y - 101) * NCOL + col], base | (u64)(x0 + 1));
        if (lb.z > 100) atomicAdd(&table[(lb.z - 101) * NCOL + col], base | (u64)(x0 + 2));
        if (lb.w > 100) atomicAdd(&table[(lb.w - 101) * NCOL + col], base | (u64)(x0 + 3));
    }

    // exp partial: wave shuffle reduce -> LDS
    for (int off = 32; off > 0; off >>= 1) es += __shfl_down(es, off, 64);
    if (lane == 0) exp_lds[tid >> 6] = (double)es;
    __syncthreads();

    // flush stage A: 4 threads per id, 8 u64 cells each -> LDS partials
    {
        const int fid  = tid >> 2;
        const int fsub = tid & 3;
        if (fid < NID) {
            u32 cnt_a = 0, sx_a = 0, syr_a = 0;
            const u64* cp = &table[fid * NCOL + fsub * 8];
#pragma unroll
            for (int j = 0; j < 8; ++j) {
                const u64 v = cp[j];
                cnt_a += (u32)(v >> 40);
                syr_a += (u32)((v >> 24) & 0xFFFFu);
                sx_a  += (u32)(v & 0xFFFFFFu);
            }
            part[fid * PSTR + fsub * 3 + 0] = cnt_a;
            part[fid * PSTR + fsub * 3 + 1] = sx_a;
            part[fid * PSTR + fsub * 3 + 2] = syr_a;
        }
    }
    __syncthreads();

    // exp: block partial -> ONE plain f64 store (block-private, no memset)
    if (tid == 0) {
        double t = 0.0;
        for (int w = 0; w < 16; ++w) t += exp_lds[w];
        g_bexp_part[blk] = t;
    }

    // flush stage B: one thread per id, plain stores (write ALL ids incl. zero)
    if (tid < NID) {
        u32 cnt_t = 0, sx_t = 0, syr_t = 0;
        for (int q = 0; q < 4; ++q) {
            cnt_t += part[tid * PSTR + q * 3 + 0];
            sx_t  += part[tid * PSTR + q * 3 + 1];
            syr_t += part[tid * PSTR + q * 3 + 2];
        }
        const size_t o = (size_t)blk * NID + tid;
        g_cnt[o] = cnt_t;
        g_sx [o] = sx_t;
        g_sy [o] = syr_t + (u32)(slice * ROWS_PER_BLOCK) * cnt_t;
    }
}

__global__ __launch_bounds__(256) void batch_kernel(
    const float* __restrict__ logits, const u32* __restrict__ g_cnt,
    const u32* __restrict__ g_sx, const u32* __restrict__ g_sy,
    const double* __restrict__ g_bexp_part,
    float* __restrict__ g_binst, double* __restrict__ g_bexp)
{
    const int b   = blockIdx.x;
    const int tid = threadIdx.x;

    // exp: combine this batch's 32 block partials in wave 0
    if (tid < 64) {
        double e = (tid < SLICES) ? g_bexp_part[b * SLICES + tid] : 0.0;
        for (int off = 32; off > 0; off >>= 1) e += __shfl_down(e, off, 64);
        if (tid == 0) g_bexp[b] = e;
    }

    float s = 0.f;
    if (tid < NID) {                   // id = 101 + tid
        u32 cnt = 0, sx = 0, sy = 0;
        for (int sl = 0; sl < SLICES; ++sl) {
            const size_t o = ((size_t)b * SLICES + sl) * NID + tid;  // coalesced over tid
            cnt += g_cnt[o];
            sx  += g_sx [o];
            sy  += g_sy [o];
        }
        if (cnt) {
            const float fc = (float)cnt;
            // identical f32 divide + truncation as the reference
            const int cx = (int)((float)sx / fc);
            const int cy = (int)((float)sy / fc);
            s = logits[(size_t)b * HWPIX + (size_t)cy * WW + cx];
        }
    }
    __shared__ float red[256];
    red[tid] = s;
    __syncthreads();
    for (int off = 128; off > 0; off >>= 1) {
        if (tid < off) red[tid] += red[tid + off];
        __syncthreads();
    }
    if (tid == 0) g_binst[b] = red[0];
}

__global__ __launch_bounds__(64) void final_kernel(
    const double* __restrict__ g_bexp, const float* __restrict__ g_binst,
    float* __restrict__ out)
{
    const int tid = threadIdx.x;
    double e = (tid < BATCH) ? g_bexp[tid] : 0.0;
    double i = (tid < BATCH) ? (double)g_binst[tid] : 0.0;
    for (int off = 32; off > 0; off >>= 1) {
        e += __shfl_down(e, off, 64);
        i += __shfl_down(i, off, 64);
    }
    if (tid == 0) {
        const double int_loss = e / (double)((double)BATCH * (double)HWPIX);
        out[0] = (float)(int_loss - i / (double)BATCH);
    }
}

extern "C" void kernel_launch(void* const* d_in, const int* in_sizes, int n_in,
                              void* d_out, int out_size, void* d_ws, size_t ws_size,
                              hipStream_t stream) {
    const float* logits = (const float*)d_in[0];
    const int*   label  = (const int*)d_in[1];
    float* out = (float*)d_out;

    // workspace layout (all regions fully rewritten every call -> no memset)
    u32*    g_cnt       = (u32*)d_ws;                       // 512*255 u32
    u32*    g_sx        = g_cnt + (size_t)NBLK * NID;
    u32*    g_sy        = g_sx  + (size_t)NBLK * NID;
    double* g_bexp_part = (double*)(g_sy + (size_t)NBLK * NID);   // 512 f64 (8-aligned)
    double* g_bexp      = g_bexp_part + NBLK;               // 16 f64
    float*  g_binst     = (float*)(g_bexp + BATCH);         // 16 f32

    accum_kernel<<<NBLK, THREADS, 0, stream>>>(logits, label, g_cnt, g_sx, g_sy, g_bexp_part);
    batch_kernel<<<BATCH, 256, 0, stream>>>(logits, g_cnt, g_sx, g_sy, g_bexp_part, g_binst, g_bexp);
    final_kernel<<<1, 64, 0, stream>>>(g_bexp, g_binst, out);
}